// Round 4
// baseline (7407.243 us; speedup 1.0000x reference)
//
#include <hip/hip_runtime.h>
#include <math.h>

#define TSTEPS 100
#define BB 256
#define FF 1024
#define NIN 784
#define NW 13           // 13*64 = 832 >= 784 bits per input row
#define FW (FF / 64)    // 16 words of spike bits per batch row
#define CHUNK_WORDS 6   // OpenBLAS sgemm KC=384 -> 6 x 64-bit words per K-chunk

typedef unsigned long long u64;

// ---------- one-time init: zero state, transpose W (stays f32) ----------
__global__ __launch_bounds__(256) void k_init(
    const float* __restrict__ W, float* __restrict__ wT,
    float* __restrict__ mem, float* __restrict__ apreT, float* __restrict__ apost,
    u64* __restrict__ spkbits, u64* __restrict__ spkT, float* __restrict__ out)
{
    int idx = blockIdx.x * 256 + threadIdx.x;          // covers NIN*FF = 802816
    {
        int f = idx & (FF - 1);
        int i = idx >> 10;
        wT[idx] = W[f * NIN + i];                      // wT[i][f] = W[f][i], f32 bits
    }
    if (idx < BB * FF)  { mem[idx] = 0.f; apost[idx] = 0.f; out[idx] = 0.f; }
    if (idx < BB * NIN) apreT[idx] = 0.f;
    if (idx < BB * FW)  spkbits[idx] = 0ull;
    if (idx < 2 * FF * 4) spkT[idx] = 0ull;
}

// ---------- Poisson encode (pure f32, NEP50): p = image*0.2f; noise < p ----------
__global__ __launch_bounds__(256) void k_encode(
    const float* __restrict__ image, const float* __restrict__ noise,
    u64* __restrict__ prebits)
{
    int tid = blockIdx.x * 256 + threadIdx.x;
    int lane = threadIdx.x & 63;
    int word = tid >> 6;           // (t*BB + b)*NW + wd
    int wd = word % NW;
    int tb = word / NW;            // t*BB + b
    int b = tb & (BB - 1);
    int i = (wd << 6) + lane;
    bool s = false;
    if (i < NIN) {
        float pf = __fmul_rn(image[b * NIN + i], 0.2f);   // single f32 rounding
        s = (noise[(size_t)tb * NIN + i] < pf);           // f32 compare
    }
    u64 m = __ballot(s);
    if (lane == 0) prebits[word] = m;
}

// ---------- transposed prebits: prebitsT[t][i][wb] (bit = batch b) ----------
__global__ __launch_bounds__(256) void k_encode_t(
    const u64* __restrict__ prebits, u64* __restrict__ prebitsT)
{
    int tid = blockIdx.x * 256 + threadIdx.x;
    int b = tid & (BB - 1);        // = threadIdx.x (blocks 256-aligned)
    int ti = tid >> 8;             // t*NIN + i
    int i = ti % NIN;
    int t = ti / NIN;
    u64 w = prebits[((size_t)t * BB + b) * NW + (i >> 6)];
    bool s = (w >> (i & 63)) & 1ull;
    u64 m = __ballot(s);
    if ((threadIdx.x & 63) == 0)
        prebitsT[(size_t)ti * 4 + ((threadIdx.x >> 6) & 3)] = m;
}

// ---------- per step, phase A (all f32, numpy ufunc-exact rounding) ----------
__global__ __launch_bounds__(256) void k_step_a(
    int t, const float* __restrict__ wT, float* __restrict__ mem,
    float* __restrict__ apreT, float* __restrict__ apost,
    const u64* __restrict__ prebits, u64* __restrict__ spkbits,
    u64* __restrict__ spkT_cur, u64* __restrict__ spkT_nxt,
    float* __restrict__ out, float dmem, float dpre, float dpost)
{
    int tid = blockIdx.x * 256 + threadIdx.x;   // b*FF + f
    int b = tid >> 10;
    int f = tid & (FF - 1);

    // apost = f32(f32(apost*decay) + spk_{t-1})
    u64 psw = spkbits[tid >> 6];
    float spk_prev = (float)((psw >> (f & 63)) & 1ull);
    float apo = __fadd_rn(__fmul_rn(apost[tid], dpost), spk_prev);
    apost[tid] = apo;

    // I[b,f] = sgemm fold: sequential f32 adds of selected wT in increasing i,
    // KC-chunked: I = ((chunk0 + chunk1) + chunk2), each chunk its own fold.
    const u64* pb = prebits + ((size_t)t * BB + b) * NW;   // wave-uniform (b uniform)
    float I = 0.0f;
    int wd = 0;
    while (wd < NW) {
        float c = 0.0f;
        int end = wd + CHUNK_WORDS; if (end > NW) end = NW;
        for (; wd < end; ++wd) {
            u64 m = pb[wd];
            const float* base = wT + (wd << 16) + f;       // (wd*64)*FF + f
            while (m) {                                    // wave-uniform loop
                int j = __builtin_ctzll(m);
                m &= m - 1;
                c = __fadd_rn(c, base[j << 10]);           // coalesced 256B/wave
            }
        }
        I = __fadd_rn(I, c);                               // C += partial (0+c0 exact)
    }

    // mem = f32(f32(mem*decay) + I); spk = mem >= 16; reset
    float mm = __fadd_rn(__fmul_rn(mem[tid], dmem), I);
    bool spk = (mm >= 16.0f);
    mem[tid] = spk ? 0.0f : mm;
    if (spk) {
        out[tid] += 1.0f;                                  // cnt += spk (exact ints)
        atomicOr(&spkT_cur[(f << 2) | (b >> 6)], 1ull << (b & 63));
    }
    u64 bal = __ballot(spk);
    if ((threadIdx.x & 63) == 0) spkbits[tid >> 6] = bal;
    if (tid < FF * 4) spkT_nxt[tid] = 0ull;                // pre-zero next parity

    // apre = f32(f32(apre*decay) + pre_t)   (stored transposed: apreT[i*256+b])
    if (tid < BB * NIN) {
        int bb = tid & (BB - 1);
        int ii = tid >> 8;
        u64 w = prebits[((size_t)t * BB + bb) * NW + (ii >> 6)];
        float pr = (float)((w >> (ii & 63)) & 1ull);
        apreT[tid] = __fadd_rn(__fmul_rn(apreT[tid], dpre), pr);
    }
}

// ---------- per step, phase B: STDP weight update (f32, einsum order = inc. b) ----------
__global__ __launch_bounds__(256) void k_step_b(
    int t, float* __restrict__ wT, const float* __restrict__ apreT,
    const float* __restrict__ apost, const u64* __restrict__ prebitsT,
    const u64* __restrict__ spkT_cur, float lrp, float lrm)
{
    int i = blockIdx.x >> 2;
    int f = ((blockIdx.x & 3) << 8) | threadIdx.x;

    // Sm[f,i] = fold_{b: pre[b,i]} apost[b,f], increasing b, f32 adds
    const u64* pt = prebitsT + ((size_t)t * NIN + i) * 4;
    float Sm = 0.0f;
    for (int wb = 0; wb < 4; ++wb) {
        u64 m = pt[wb];
        const float* ab = apost + (wb << 16) + f;    // (wb*64)*FF + f
        while (m) {
            int j = __builtin_ctzll(m);
            m &= m - 1;
            Sm = __fadd_rn(Sm, ab[j << 10]);         // coalesced 256B/wave
        }
    }
    // Sp[f,i] = fold_{b: spk[b,f]} apre[b,i], increasing b, f32 adds
    const u64* st = spkT_cur + (f << 2);
    const float* ar = apreT + (i << 8);              // row i of apreT, 1KB, L1-hot
    float Sp = 0.0f;
    for (int wb = 0; wb < 4; ++wb) {
        u64 m = st[wb];
        while (m) {
            int j = __builtin_ctzll(m);
            m &= m - 1;
            Sp = __fadd_rn(Sp, ar[(wb << 6) + j]);
        }
    }
    int wi = (i << 10) | f;
    float w = wT[wi];
    w = __fadd_rn(w, __fmul_rn(lrp, Sp));            // w + dw_plus
    w = __fsub_rn(w, __fmul_rn(lrm, Sm));            // ... - dw_minus
    w = fminf(fmaxf(w, 0.0f), 1.0f);                 // np.clip
    wT[wi] = w;
}

extern "C" void kernel_launch(void* const* d_in, const int* in_sizes, int n_in,
                              void* d_out, int out_size, void* d_ws, size_t ws_size,
                              hipStream_t stream)
{
    const float* image = (const float*)d_in[0];   // (B,1,28,28) f32
    const float* W     = (const float*)d_in[1];   // (F,784) f32
    const float* noise = (const float*)d_in[2];   // (T,B,1,28,28) f32
    float* out = (float*)d_out;                   // (B,F) f32 spike counts

    char* p = (char*)d_ws;
    float* wT      = (float*)p; p += (size_t)NIN * FF * 4;          // 3.2 MB
    float* mem     = (float*)p; p += (size_t)BB * FF * 4;           // 1 MB
    float* apreT   = (float*)p; p += (size_t)BB * NIN * 4;          // 0.8 MB
    float* apost   = (float*)p; p += (size_t)BB * FF * 4;           // 1 MB
    u64* prebits   = (u64*)p;   p += (size_t)TSTEPS * BB * NW * 8;  // 2.66 MB
    u64* prebitsT  = (u64*)p;   p += (size_t)TSTEPS * NIN * 4 * 8;  // 2.5 MB
    u64* spkbits   = (u64*)p;   p += (size_t)BB * FW * 8;           // 32 KB
    u64* spkT      = (u64*)p;   p += (size_t)2 * FF * 4 * 8;        // 64 KB

    // f32 scalars, numpy-NEP50 faithful: scalar cast to f32 at the ufunc
    float dmem = (float)exp(-1.0 / 20.0);   // np.float32(np.exp(-0.05))
    float dpre = dmem, dpost = dmem;
    float lrp = (float)(0.01 / 256.0);      // f32(LR_POST / b)
    float lrm = (float)(0.012 / 256.0);     // f32(LR_PRE / b)

    k_init<<<(NIN * FF) / 256, 256, 0, stream>>>(W, wT, mem, apreT, apost, spkbits, spkT, out);
    k_encode<<<(TSTEPS * BB * NW * 64) / 256, 256, 0, stream>>>(image, noise, prebits);
    k_encode_t<<<(TSTEPS * NIN * BB) / 256, 256, 0, stream>>>(prebits, prebitsT);

    for (int t = 0; t < TSTEPS; ++t) {
        u64* cur = spkT + (size_t)(t & 1) * FF * 4;
        u64* nxt = spkT + (size_t)((t + 1) & 1) * FF * 4;
        k_step_a<<<(BB * FF) / 256, 256, 0, stream>>>(
            t, wT, mem, apreT, apost, prebits, spkbits, cur, nxt, out, dmem, dpre, dpost);
        if (t < TSTEPS - 1)
            k_step_b<<<NIN * 4, 256, 0, stream>>>(
                t, wT, apreT, apost, prebitsT, cur, lrp, lrm);
    }
}

// Round 5
// 5561.111 us; speedup vs baseline: 1.3320x; 1.3320x over previous
//
#include <hip/hip_runtime.h>
#include <math.h>

#define TSTEPS 100
#define BB 256
#define FF 1024
#define NIN 784
#define NW 13           // 13*64 = 832 >= 784 bits per input row
#define FW (FF / 64)    // 16 words of spike bits per batch row
#define CAPA 192        // max pre-spikes per (t,b)  (mean ~78, 9-sigma safe)
#define CAPB 128        // max pre-spikes per (t,i)  (mean ~26, 9-sigma safe)

typedef unsigned long long u64;

// ---------- one-time init: zero state, transpose W (stays f32) ----------
__global__ __launch_bounds__(256) void k_init(
    const float* __restrict__ W, float* __restrict__ wT,
    float* __restrict__ mem, float* __restrict__ apre_rep, float* __restrict__ apost,
    u64* __restrict__ spkbits, u64* __restrict__ spkT, float* __restrict__ out)
{
    int idx = blockIdx.x * 256 + threadIdx.x;          // covers NIN*FF = 802816
    {
        int f = idx & (FF - 1);
        int i = idx >> 10;
        wT[idx] = W[f * NIN + i];                      // wT[i][f] = W[f][i], f32 bits
    }
    apre_rep[idx] = 0.f;                               // 8 copies = 2*802816 elems
    apre_rep[idx + NIN * FF] = 0.f;
    if (idx < BB * FF)  { mem[idx] = 0.f; apost[idx] = 0.f; out[idx] = 0.f; }
    if (idx < BB * FW)  spkbits[idx] = 0ull;
    if (idx < 2 * FF * 4) spkT[idx] = 0ull;
}

// ---------- Poisson encode (pure f32): p = image*0.2f; noise < p ----------
__global__ __launch_bounds__(256) void k_encode(
    const float* __restrict__ image, const float* __restrict__ noise,
    u64* __restrict__ prebits)
{
    int tid = blockIdx.x * 256 + threadIdx.x;
    int lane = threadIdx.x & 63;
    int word = tid >> 6;           // (t*BB + b)*NW + wd
    int wd = word % NW;
    int tb = word / NW;            // t*BB + b
    int b = tb & (BB - 1);
    int i = (wd << 6) + lane;
    bool s = false;
    if (i < NIN) {
        float pf = __fmul_rn(image[b * NIN + i], 0.2f);   // single f32 rounding
        s = (noise[(size_t)tb * NIN + i] < pf);           // f32 compare
    }
    u64 m = __ballot(s);
    if (lane == 0) prebits[word] = m;
}

// ---------- transposed prebits: prebitsT[t][i][wb] (bit = batch b) ----------
__global__ __launch_bounds__(256) void k_encode_t(
    const u64* __restrict__ prebits, u64* __restrict__ prebitsT)
{
    int tid = blockIdx.x * 256 + threadIdx.x;
    int b = tid & (BB - 1);
    int ti = tid >> 8;             // t*NIN + i
    int i = ti % NIN;
    int t = ti / NIN;
    u64 w = prebits[((size_t)t * BB + b) * NW + (i >> 6)];
    bool s = (w >> (i & 63)) & 1ull;
    u64 m = __ballot(s);
    if ((threadIdx.x & 63) == 0)
        prebitsT[(size_t)ti * 4 + ((threadIdx.x >> 6) & 3)] = m;
}

// ---------- set-bit index lists per (t,b): ascending i, with KC=384 chunk marks ----------
__global__ __launch_bounds__(256) void k_lists(
    const u64* __restrict__ prebits, unsigned short* __restrict__ idxA,
    unsigned short* __restrict__ cntA)
{
    int tb = blockIdx.x * 256 + threadIdx.x;   // t*BB+b, grid exactly 25600
    const u64* pb = prebits + (size_t)tb * NW;
    unsigned short* ia = idxA + (size_t)tb * CAPA;
    int n = 0, c1 = 0, c2 = 0;
    for (int wd = 0; wd < NW; ++wd) {
        u64 m = pb[wd];
        int boff = wd << 6;
        while (m) {
            int j = __builtin_ctzll(m); m &= m - 1;
            if (n < CAPA) ia[n] = (unsigned short)(boff + j);
            ++n;
        }
        if (wd == 5)  c1 = n;     // i < 384 boundary (chunk0)
        if (wd == 11) c2 = n;     // i < 768 boundary (chunk1)
    }
    if (n > CAPA) n = CAPA;
    if (c2 > n) c2 = n;
    if (c1 > c2) c1 = c2;
    cntA[tb * 4 + 0] = (unsigned short)c1;
    cntA[tb * 4 + 1] = (unsigned short)c2;
    cntA[tb * 4 + 2] = (unsigned short)n;
}

// ---------- set-bit b-lists per (t,i): ascending b ----------
__global__ __launch_bounds__(256) void k_listsT(
    const u64* __restrict__ prebitsT, unsigned char* __restrict__ idxB,
    unsigned short* __restrict__ cntB)
{
    int ti = blockIdx.x * 256 + threadIdx.x;   // t*NIN+i
    if (ti >= TSTEPS * NIN) return;
    const u64* pt = prebitsT + (size_t)ti * 4;
    unsigned char* ib = idxB + (size_t)ti * CAPB;
    int n = 0;
    for (int wb = 0; wb < 4; ++wb) {
        u64 m = pt[wb];
        int boff = wb << 6;
        while (m) {
            int j = __builtin_ctzll(m); m &= m - 1;
            if (n < CAPB) ib[n] = (unsigned char)(boff + j);
            ++n;
        }
    }
    cntB[ti] = (unsigned short)(n > CAPB ? CAPB : n);
}

// ---------- per step, phase A (f-slice g = bid&7 pinned to XCD g) ----------
__global__ __launch_bounds__(128) void k_step_a(
    int t, const float* __restrict__ wT, float* __restrict__ mem,
    float* __restrict__ apre_rep, float* __restrict__ apost,
    const u64* __restrict__ prebits,
    const unsigned short* __restrict__ idxA, const unsigned short* __restrict__ cntA,
    u64* __restrict__ spkbits, u64* __restrict__ spkT_cur, u64* __restrict__ spkT_nxt,
    float* __restrict__ out, float dmem, float dpre, float dpost)
{
    int bid = blockIdx.x;            // 0..2047
    int g = bid & 7;                 // XCD-pinned f-group (128 cols)
    int b = bid >> 3;                // 0..255
    int f = (g << 7) | threadIdx.x;
    int tid = (b << 10) | f;         // logical b*1024+f

    // apost = f32(f32(apost*decay) + spk_{t-1})
    u64 psw = spkbits[tid >> 6];
    float spk_prev = (float)((psw >> (f & 63)) & 1ull);
    float apo = __fadd_rn(__fmul_rn(apost[tid], dpost), spk_prev);
    apost[tid] = apo;

    // I = ((chunk0 + chunk1) + chunk2), each chunk a sequential f32 fold
    // over ascending pre-spike indices (identical order to round-4 pass).
    const unsigned short* ia = idxA + (size_t)(t * BB + b) * CAPA;
    const unsigned short* ca = cntA + (size_t)(t * BB + b) * 4;
    int c1 = ca[0], c2 = ca[1], c3 = ca[2];
    float I = 0.0f;
    int k = 0;
    {
        float c = 0.0f;
        #pragma unroll 4
        for (; k < c1; ++k) c = __fadd_rn(c, wT[((int)ia[k] << 10) + f]);
        I = __fadd_rn(I, c);
    }
    {
        float c = 0.0f;
        #pragma unroll 4
        for (; k < c2; ++k) c = __fadd_rn(c, wT[((int)ia[k] << 10) + f]);
        I = __fadd_rn(I, c);
    }
    {
        float c = 0.0f;
        #pragma unroll 4
        for (; k < c3; ++k) c = __fadd_rn(c, wT[((int)ia[k] << 10) + f]);
        I = __fadd_rn(I, c);
    }

    float mm = __fadd_rn(__fmul_rn(mem[tid], dmem), I);
    bool spk = (mm >= 16.0f);
    mem[tid] = spk ? 0.0f : mm;
    if (spk) {
        out[tid] += 1.0f;
        atomicOr(&spkT_cur[(f << 2) | (b >> 6)], 1ull << (b & 63));
    }
    u64 bal = __ballot(spk);
    if ((threadIdx.x & 63) == 0) spkbits[tid >> 6] = bal;
    if (threadIdx.x < 2) spkT_nxt[bid * 2 + threadIdx.x] = 0ull;  // 2048*2 = 4096 words

    // apre update, replicated per-XCD copy g, coalesced contiguous chunk b*784..
    float* ap = apre_rep + (size_t)g * (BB * NIN);
    for (int e = b * NIN + threadIdx.x; e < (b + 1) * NIN; e += 128) {
        int bb = e & (BB - 1), ii = e >> 8;
        u64 w = prebits[((size_t)t * BB + bb) * NW + (ii >> 6)];
        float pr = (float)((w >> (ii & 63)) & 1ull);
        ap[e] = __fadd_rn(__fmul_rn(ap[e], dpre), pr);
    }
}

// ---------- per step, phase B: STDP update (f-slice g = bid&7 pinned) ----------
__global__ __launch_bounds__(128) void k_step_b(
    int t, float* __restrict__ wT, const float* __restrict__ apre_rep,
    const float* __restrict__ apost,
    const unsigned char* __restrict__ idxB, const unsigned short* __restrict__ cntB,
    const u64* __restrict__ spkT_cur, float lrp, float lrm)
{
    int bid = blockIdx.x;            // 0..6271
    int g = bid & 7;
    int i = bid >> 3;                // 0..783
    int f = (g << 7) | threadIdx.x;

    // Sm = fold_{b in pre(i)} apost[b,f], ascending b, counted+unrolled
    const unsigned char* ib = idxB + (size_t)(t * NIN + i) * CAPB;
    int cb = cntB[t * NIN + i];
    float Sm = 0.0f;
    #pragma unroll 4
    for (int k = 0; k < cb; ++k)
        Sm = __fadd_rn(Sm, apost[((int)ib[k] << 10) + f]);

    // Sp = fold_{b in spk(f)} apre[b,i], ascending b (per-lane masks, L1-hot row)
    const u64* st = spkT_cur + (f << 2);
    const float* ar = apre_rep + (size_t)g * (BB * NIN) + (i << 8);
    float Sp = 0.0f;
    for (int wb = 0; wb < 4; ++wb) {
        u64 m = st[wb];
        while (m) {
            int j = __builtin_ctzll(m); m &= m - 1;
            Sp = __fadd_rn(Sp, ar[(wb << 6) + j]);
        }
    }
    int wi = (i << 10) | f;
    float w = wT[wi];
    w = __fadd_rn(w, __fmul_rn(lrp, Sp));
    w = __fsub_rn(w, __fmul_rn(lrm, Sm));
    w = fminf(fmaxf(w, 0.0f), 1.0f);
    wT[wi] = w;
}

extern "C" void kernel_launch(void* const* d_in, const int* in_sizes, int n_in,
                              void* d_out, int out_size, void* d_ws, size_t ws_size,
                              hipStream_t stream)
{
    const float* image = (const float*)d_in[0];
    const float* W     = (const float*)d_in[1];
    const float* noise = (const float*)d_in[2];
    float* out = (float*)d_out;

    char* p = (char*)d_ws;
    float* wT       = (float*)p; p += (size_t)NIN * FF * 4;             // 3.2 MB
    float* mem      = (float*)p; p += (size_t)BB * FF * 4;              // 1 MB
    float* apre_rep = (float*)p; p += (size_t)8 * BB * NIN * 4;         // 6.4 MB (8 XCD copies)
    float* apost    = (float*)p; p += (size_t)BB * FF * 4;              // 1 MB
    u64* prebits    = (u64*)p;   p += (size_t)TSTEPS * BB * NW * 8;     // 2.66 MB
    u64* prebitsT   = (u64*)p;   p += (size_t)TSTEPS * NIN * 4 * 8;     // 2.5 MB
    u64* spkbits    = (u64*)p;   p += (size_t)BB * FW * 8;              // 32 KB
    u64* spkT       = (u64*)p;   p += (size_t)2 * FF * 4 * 8;           // 64 KB
    unsigned short* idxA = (unsigned short*)p; p += (size_t)TSTEPS * BB * CAPA * 2;  // 9.8 MB
    unsigned short* cntA = (unsigned short*)p; p += (size_t)TSTEPS * BB * 4 * 2;     // 0.2 MB
    unsigned char*  idxB = (unsigned char*)p;  p += (size_t)TSTEPS * NIN * CAPB;     // 10 MB
    unsigned short* cntB = (unsigned short*)p; p += (size_t)TSTEPS * NIN * 2;        // 0.16 MB

    float dmem = (float)exp(-1.0 / 20.0);   // np.float32(np.exp(-0.05))
    float dpre = dmem, dpost = dmem;
    float lrp = (float)(0.01 / 256.0);
    float lrm = (float)(0.012 / 256.0);

    k_init<<<(NIN * FF) / 256, 256, 0, stream>>>(W, wT, mem, apre_rep, apost, spkbits, spkT, out);
    k_encode<<<(TSTEPS * BB * NW * 64) / 256, 256, 0, stream>>>(image, noise, prebits);
    k_encode_t<<<(TSTEPS * NIN * BB) / 256, 256, 0, stream>>>(prebits, prebitsT);
    k_lists<<<(TSTEPS * BB) / 256, 256, 0, stream>>>(prebits, idxA, cntA);
    k_listsT<<<(TSTEPS * NIN + 255) / 256, 256, 0, stream>>>(prebitsT, idxB, cntB);

    for (int t = 0; t < TSTEPS; ++t) {
        u64* cur = spkT + (size_t)(t & 1) * FF * 4;
        u64* nxt = spkT + (size_t)((t + 1) & 1) * FF * 4;
        k_step_a<<<BB * 8, 128, 0, stream>>>(
            t, wT, mem, apre_rep, apost, prebits, idxA, cntA,
            spkbits, cur, nxt, out, dmem, dpre, dpost);
        if (t < TSTEPS - 1)
            k_step_b<<<NIN * 8, 128, 0, stream>>>(
                t, wT, apre_rep, apost, idxB, cntB, cur, lrp, lrm);
    }
}